// Round 18
// baseline (268.857 us; speedup 1.0000x reference)
//
#include <hip/hip_runtime.h>
#include <hip/hip_bf16.h>
#include <stdint.h>

#define SEQ    2048
#define DMODEL 4096
#define NH     32
#define NKVH   8
#define HDIM   128
#define KVD    (NKVH*HDIM)   // 1024
#define QD     (NH*HDIM)     // 4096
#define QKVN   (QD + 2*KVD)  // 6144 fused projection columns
#define ASCALE 0.08838834764831845f

typedef __attribute__((ext_vector_type(8))) short s8v;   // 8 bf16
typedef __attribute__((ext_vector_type(4))) short s4v;   // 4 bf16
typedef __attribute__((ext_vector_type(4))) float f4v;   // 4 f32

#define MFMA16(acc, a, b) \
  asm("v_mfma_f32_16x16x32_bf16 %0, %1, %2, %0" : "+v"(acc) : "v"(a), "v"(b))

#define SFENCE() __builtin_amdgcn_sched_barrier(0)

__device__ __forceinline__ void gl2lds16(const void* g, void* l) {
  __builtin_amdgcn_global_load_lds(
      (const __attribute__((address_space(1))) void*)g,
      (__attribute__((address_space(3))) void*)l, 16, 0, 0);
}

// ---------------- merged f32 -> bf16 convert + fc/fs float2 pack (one launch) ----------------
__global__ __launch_bounds__(256) void k_cvt5(const float* __restrict__ x,
                                              const float* __restrict__ wq,
                                              const float* __restrict__ wk,
                                              const float* __restrict__ wv,
                                              const float* __restrict__ wo,
                                              const float* __restrict__ fc,
                                              const float* __restrict__ fs,
                                              __hip_bfloat16* __restrict__ xb,
                                              __hip_bfloat16* __restrict__ wf,
                                              __hip_bfloat16* __restrict__ wob,
                                              float2* __restrict__ fcs2) {
  int i = blockIdx.x * 256 + threadIdx.x;
  if (i >= 6291456) {                      // region 6: pack cos/sin interleaved (f32 copy)
    int j = i - 6291456;                   // 0..16383, 8 pairs each
    const float4* pc = (const float4*)fc + (size_t)j * 2;
    const float4* ps = (const float4*)fs + (size_t)j * 2;
    float4 c0 = pc[0], c1 = pc[1], s0 = ps[0], s1 = ps[1];
    float2* o = fcs2 + (size_t)j * 8;
    o[0] = {c0.x, s0.x}; o[1] = {c0.y, s0.y}; o[2] = {c0.z, s0.z}; o[3] = {c0.w, s0.w};
    o[4] = {c1.x, s1.x}; o[5] = {c1.y, s1.y}; o[6] = {c1.z, s1.z}; o[7] = {c1.w, s1.w};
    return;
  }
  const float* src;
  __hip_bfloat16* dst;
  float scale = 1.0f;
  if (i < 1048576)       { src = x;  dst = xb; }
  else if (i < 3145728)  { src = wq; dst = wf;  i -= 1048576; scale = ASCALE; }
  else if (i < 3670016)  { src = wk; dst = wf + (size_t)QD * DMODEL;  i -= 3145728; }
  else if (i < 4194304)  { src = wv; dst = wf + (size_t)(QD + KVD) * DMODEL; i -= 3670016; }
  else                   { src = wo; dst = wob; i -= 4194304; }
  const float4* p = (const float4*)src + (size_t)i * 2;
  float4 a = p[0], b = p[1];
  union { __hip_bfloat16 h[8]; s8v v; } o;
  o.h[0] = __float2bfloat16(a.x * scale); o.h[1] = __float2bfloat16(a.y * scale);
  o.h[2] = __float2bfloat16(a.z * scale); o.h[3] = __float2bfloat16(a.w * scale);
  o.h[4] = __float2bfloat16(b.x * scale); o.h[5] = __float2bfloat16(b.y * scale);
  o.h[6] = __float2bfloat16(b.z * scale); o.h[7] = __float2bfloat16(b.w * scale);
  *(s8v*)(dst + (size_t)i * 8) = o.v;
}

// ---------------- fused QKV projection: 1-barrier/tile + WAVE ANTI-PHASING ----------------
// Waves 0-3 process k-halves in order (0,32); waves 4-7 in order (32,0). Waves w and
// w+4 share a SIMD -> at any instant one wave of the pair is in its ds_read burst
// while the other is in its MFMA burst: LDS pipe and matrix pipe overlap instead of
// alternating. Per-element accumulation = same two summand groups, swapped order
// (f32-commutative; absmax may move a few e-5).
__global__ __launch_bounds__(512, 2) void k_qkv(const __hip_bfloat16* __restrict__ A,
                                                const __hip_bfloat16* __restrict__ W,
                                                const float2* __restrict__ fcs2,
                                                __hip_bfloat16* __restrict__ Qb,
                                                __hip_bfloat16* __restrict__ Kc,
                                                __hip_bfloat16* __restrict__ Vt) {
  __shared__ __align__(16) __hip_bfloat16 sm[2][256 * 64 + 192 * 64];
  const int t5 = threadIdx.x;
  const int wave = t5 >> 6, lane = t5 & 63;
  const int lrow = lane & 15, kq = lane >> 4;
  const int wm = wave >> 1, wn = wave & 1;          // 4M x 2N
  const int mt = blockIdx.x & 7, nt = blockIdx.x >> 3;
  const int m0 = mt * 256, n0 = nt * 192;
  const int ka = (wave >= 4) ? 32 : 0;              // anti-phase k-half order
  const int kb = ka ^ 32;

  auto stageA = [&](int p, int kt) {
#pragma unroll
    for (int it = 0; it < 4; ++it) {
      int chunk = it * 512 + t5;
      int r = chunk >> 3, cc = ((chunk & 7) ^ (r & 7)) * 8;
      gl2lds16(A + (size_t)(m0 + r) * DMODEL + kt * 64 + cc,
               (char*)&sm[p][0] + it * 8192 + wave * 1024);
    }
  };
  auto stageB = [&](int p, int kt) {
#pragma unroll
    for (int it = 0; it < 3; ++it) {
      int chunk = it * 512 + t5;
      int r = chunk >> 3, cc = ((chunk & 7) ^ (r & 7)) * 8;
      gl2lds16(W + (size_t)(n0 + r) * DMODEL + kt * 64 + cc,
               (char*)&sm[p][0] + 32768 + it * 8192 + wave * 1024);
    }
  };

  f4v acc[4][6] = {};

  stageA(0, 0); stageB(0, 0);    // prologue: tile 0 only (depth-1)

  const int NT = DMODEL / 64;
#pragma unroll 2
  for (int t = 0; t < NT; ++t) {
    const int p = t & 1;
    const __hip_bfloat16* As = &sm[p][0];
    const __hip_bfloat16* Bs = &sm[p][256 * 64];

    // boundary: tile t's stages landed (issued a full tile ago in steady state)
    __builtin_amdgcn_sched_barrier(0);
    asm volatile("s_waitcnt vmcnt(0)" ::: "memory");
    __builtin_amdgcn_s_barrier();
    __builtin_amdgcn_sched_barrier(0);

    // stage t+1 into the opposite buffer: hazard-free post-barrier
    if (t + 1 < NT) { stageA(p ^ 1, t + 1); stageB(p ^ 1, t + 1); }
    SFENCE();   // keep stages issued ahead of the body

    // body: first k-half (ka) reads+MFMA, then second (kb) — order is per-wave
    s8v a0[4], b0[6], a1[4], b1[6];
#pragma unroll
    for (int m = 0; m < 4; ++m) {
      int row = wm * 64 + m * 16 + lrow;
      a0[m] = *(const s8v*)&As[row * 64 + ((ka + kq * 8) ^ ((row & 7) << 3))];
    }
#pragma unroll
    for (int n = 0; n < 6; ++n) {
      int row = wn * 96 + n * 16 + lrow;
      b0[n] = *(const s8v*)&Bs[row * 64 + ((ka + kq * 8) ^ ((row & 7) << 3))];
    }
    __builtin_amdgcn_s_setprio(1);
#pragma unroll
    for (int m = 0; m < 4; ++m)
#pragma unroll
      for (int n = 0; n < 6; ++n) MFMA16(acc[m][n], a0[m], b0[n]);
    __builtin_amdgcn_s_setprio(0);
    SFENCE();
#pragma unroll
    for (int m = 0; m < 4; ++m) {
      int row = wm * 64 + m * 16 + lrow;
      a1[m] = *(const s8v*)&As[row * 64 + ((kb + kq * 8) ^ ((row & 7) << 3))];
    }
#pragma unroll
    for (int n = 0; n < 6; ++n) {
      int row = wn * 96 + n * 16 + lrow;
      b1[n] = *(const s8v*)&Bs[row * 64 + ((kb + kq * 8) ^ ((row & 7) << 3))];
    }
    __builtin_amdgcn_s_setprio(1);
#pragma unroll
    for (int m = 0; m < 4; ++m)
#pragma unroll
      for (int n = 0; n < 6; ++n) MFMA16(acc[m][n], a1[m], b1[n]);
    __builtin_amdgcn_s_setprio(0);
  }

  // epilogue: Q/K fused rope (float2 cos/sin); V transposed
#pragma unroll
  for (int m = 0; m < 4; ++m)
#pragma unroll
    for (int n = 0; n < 6; ++n) {
      int c = n0 + wn * 96 + n * 16 + lrow;
      int r0 = m0 + wm * 64 + m * 16 + kq * 4;
      if (c < QD + KVD) {
        const int ii = (c & 127) >> 1;
        const bool odd = c & 1;
        float vout[4];
#pragma unroll
        for (int j = 0; j < 4; ++j) {
          float v = acc[m][n][j];
          float pvt = __shfl_xor(v, 1, 64);
          float2 cs = fcs2[(size_t)(r0 + j) * 64 + ii];
          vout[j] = odd ? (pvt * cs.y + v * cs.x) : (v * cs.x - pvt * cs.y);
        }
        if (c < QD) {
#pragma unroll
          for (int j = 0; j < 4; ++j)
            Qb[(size_t)(r0 + j) * QD + c] = __float2bfloat16(vout[j]);
        } else {
#pragma unroll
          for (int j = 0; j < 4; ++j)
            Kc[(size_t)(r0 + j) * KVD + (c - QD)] = __float2bfloat16(vout[j]);
        }
      } else {
        union { __hip_bfloat16 b[4]; s4v v; } u;
#pragma unroll
        for (int j = 0; j < 4; ++j) u.b[j] = __float2bfloat16(acc[m][n][j]);
        *(s4v*)&Vt[(size_t)(c - QD - KVD) * SEQ + r0] = u.v;
      }
    }
}

// ---------------- O-projection: 1-barrier/tile + wave anti-phasing, 128x256 ----------------
__global__ __launch_bounds__(512, 2) void k_oproj(const __hip_bfloat16* __restrict__ A,
                                                  const __hip_bfloat16* __restrict__ B,
                                                  float* __restrict__ C) {
  __shared__ __align__(16) __hip_bfloat16 sm[2][128 * 64 + 256 * 64];
  const int t5 = threadIdx.x;
  const int wave = t5 >> 6, lane = t5 & 63;
  const int lrow = lane & 15, kq = lane >> 4;
  const int wm = wave >> 2, wn = wave & 3;
  const int m0 = blockIdx.y * 128, n0 = blockIdx.x * 256;
  const int ka = (wave >= 4) ? 32 : 0;
  const int kb = ka ^ 32;

  auto stageA = [&](int p, int kt) {
#pragma unroll
    for (int it = 0; it < 2; ++it) {
      int chunk = it * 512 + t5;
      int r = chunk >> 3, cc = ((chunk & 7) ^ (r & 7)) * 8;
      gl2lds16(A + (size_t)(m0 + r) * QD + kt * 64 + cc,
               (char*)&sm[p][0] + it * 8192 + wave * 1024);
    }
  };
  auto stageB = [&](int p, int kt) {
#pragma unroll
    for (int it = 0; it < 4; ++it) {
      int chunk = it * 512 + t5;
      int r = chunk >> 3, cc = ((chunk & 7) ^ (r & 7)) * 8;
      gl2lds16(B + (size_t)(n0 + r) * QD + kt * 64 + cc,
               (char*)&sm[p][0] + 16384 + it * 8192 + wave * 1024);
    }
  };

  f4v acc[4][4] = {};

  stageA(0, 0); stageB(0, 0);    // prologue: tile 0 only

  const int NT = QD / 64;
#pragma unroll 2
  for (int t = 0; t < NT; ++t) {
    const int p = t & 1;
    const __hip_bfloat16* As = &sm[p][0];
    const __hip_bfloat16* Bs = &sm[p][128 * 64];

    __builtin_amdgcn_sched_barrier(0);
    asm volatile("s_waitcnt vmcnt(0)" ::: "memory");
    __builtin_amdgcn_s_barrier();
    __builtin_amdgcn_sched_barrier(0);

    if (t + 1 < NT) { stageA(p ^ 1, t + 1); stageB(p ^ 1, t + 1); }
    SFENCE();

    s8v a0[4], b0[4], a1[4], b1[4];
#pragma unroll
    for (int m = 0; m < 4; ++m) {
      int row = wm * 64 + m * 16 + lrow;
      a0[m] = *(const s8v*)&As[row * 64 + ((ka + kq * 8) ^ ((row & 7) << 3))];
    }
#pragma unroll
    for (int n = 0; n < 4; ++n) {
      int row = wn * 64 + n * 16 + lrow;
      b0[n] = *(const s8v*)&Bs[row * 64 + ((ka + kq * 8) ^ ((row & 7) << 3))];
    }
    __builtin_amdgcn_s_setprio(1);
#pragma unroll
    for (int m = 0; m < 4; ++m)
#pragma unroll
      for (int n = 0; n < 4; ++n) MFMA16(acc[m][n], a0[m], b0[n]);
    __builtin_amdgcn_s_setprio(0);
    SFENCE();
#pragma unroll
    for (int m = 0; m < 4; ++m) {
      int row = wm * 64 + m * 16 + lrow;
      a1[m] = *(const s8v*)&As[row * 64 + ((kb + kq * 8) ^ ((row & 7) << 3))];
    }
#pragma unroll
    for (int n = 0; n < 4; ++n) {
      int row = wn * 64 + n * 16 + lrow;
      b1[n] = *(const s8v*)&Bs[row * 64 + ((kb + kq * 8) ^ ((row & 7) << 3))];
    }
    __builtin_amdgcn_s_setprio(1);
#pragma unroll
    for (int m = 0; m < 4; ++m)
#pragma unroll
      for (int n = 0; n < 4; ++n) MFMA16(acc[m][n], a1[m], b1[n]);
    __builtin_amdgcn_s_setprio(0);
  }

#pragma unroll
  for (int m = 0; m < 4; ++m)
#pragma unroll
    for (int n = 0; n < 4; ++n)
#pragma unroll
      for (int j = 0; j < 4; ++j) {
        int r = m0 + wm * 64 + m * 16 + kq * 4 + j;
        int c = n0 + wn * 64 + n * 16 + lrow;
        C[(size_t)r * DMODEL + c] = acc[m][n][j];
      }
}

// ---------------- causal flash attention: R13 verified form (FINAL) ----------------
__global__ __launch_bounds__(256, 2) void k_flash(const __hip_bfloat16* __restrict__ Q,
                                                  const __hip_bfloat16* __restrict__ Kb,
                                                  const __hip_bfloat16* __restrict__ Vtg,
                                                  __hip_bfloat16* __restrict__ O) {
  __shared__ __align__(16) __hip_bfloat16 Ks[2][64 * 128];
  __shared__ __align__(16) __hip_bfloat16 Vs[144 * 64];   // rows 128..143 = ones
  __shared__ __align__(16) __hip_bfloat16 Ps[4][16 * 64];
  const int qp = blockIdx.x, h = blockIdx.y, g = h >> 2;
  const int t = threadIdx.x, wave = t >> 6, lane = t & 63;
  const int lrow = lane & 15, kq = lane >> 4;
  const int qtA = qp, qtB = 31 - qp;

  s8v qfA[4], qfB[4];
  {
    const int qrA = qtA * 64 + wave * 16 + lrow;
    const int qrB = qtB * 64 + wave * 16 + lrow;
#pragma unroll
    for (int tt = 0; tt < 4; ++tt) {
      qfA[tt] = *(const s8v*)(Q + (size_t)qrA * QD + h * HDIM + tt * 32 + kq * 8);
      qfB[tt] = *(const s8v*)(Q + (size_t)qrB * QD + h * HDIM + tt * 32 + kq * 8);
    }
  }

  if (t < 128) {
    union { __hip_bfloat16 h8[8]; s8v v; } one;
#pragma unroll
    for (int e = 0; e < 8; ++e) one.h8[e] = __float2bfloat16(1.0f);
    *(s8v*)&Vs[128 * 64 + t * 8] = one.v;
  }

  f4v oA[9] = {}, oB[9] = {};   // [8] = l accumulator (ones-column)
  float mA = -1e30f, mB = -1e30f;

  auto stage_k = [&](int buf, int kv) {
#pragma unroll
    for (int it = 0; it < 4; ++it) {
      int chunk = it * 256 + t;
      int r = chunk >> 4, cc = ((chunk & 15) ^ (r & 7)) * 8;
      gl2lds16(Kb + (size_t)(kv * 64 + r) * KVD + g * HDIM + cc,
               (char*)&Ks[buf][0] + it * 4096 + wave * 1024);
    }
  };
  auto stage_v = [&](int kv) {
#pragma unroll
    for (int it = 0; it < 4; ++it) {
      int chunk = it * 256 + t;
      int d = chunk >> 3, cc = ((chunk & 7) ^ (d & 7)) * 8;
      gl2lds16(Vtg + (size_t)(g * HDIM + d) * SEQ + kv * 64 + cc,
               (char*)Vs + it * 4096 + wave * 1024);
    }
  };

  auto soft_pv = [&](f4v (&s)[4], int qt, int kv, f4v (&acc_o)[9], float& mrun) {
    __hip_bfloat16* P = &Ps[wave][0];
    const bool diag = (kv == qt);
    const int qi = qt * 64 + wave * 16 + lrow;
    const int swz = (lrow & 7) << 3;
    float pv[4][4];
    float mx = -1e30f;
#pragma unroll
    for (int n = 0; n < 4; ++n)
#pragma unroll
      for (int j = 0; j < 4; ++j) {
        float v = s[n][j];
        if (diag) {
          int ki = kv * 64 + n * 16 + kq * 4 + j;
          if (ki > qi) v = -1e30f;
        }
        pv[n][j] = v;
        mx = fmaxf(mx, v);
      }
    mx = fmaxf(mx, __shfl_xor(mx, 16, 64));
    mx = fmaxf(mx, __shfl_xor(mx, 32, 64));
    if (!__all(mx <= mrun)) {
      float mnew = fmaxf(mrun, mx);
      float fsc = __expf(mrun - mnew);
      mrun = mnew;
      float fj[4];
#pragma unroll
      for (int j = 0; j < 4; ++j) fj[j] = __shfl(fsc, kq * 4 + j, 64);
#pragma unroll
      for (int n = 0; n < 9; ++n) {
        acc_o[n][0] *= fj[0]; acc_o[n][1] *= fj[1];
        acc_o[n][2] *= fj[2]; acc_o[n][3] *= fj[3];
      }
    }
    asm volatile("" ::: "memory");
#pragma unroll
    for (int n = 0; n < 4; ++n) {
      union { __hip_bfloat16 b[4]; s4v v; } u;
#pragma unroll
      for (int j = 0; j < 4; ++j) u.b[j] = __float2bfloat16(__expf(pv[n][j] - mrun));
      *(s4v*)&P[lrow * 64 + ((n * 16 + kq * 4) ^ swz)] = u.v;
    }
    asm volatile("" ::: "memory");
#pragma unroll
    for (int tt = 0; tt < 2; ++tt) {
      s8v pa = *(const s8v*)&P[lrow * 64 + ((tt * 32 + kq * 8) ^ swz)];
#pragma unroll
      for (int n = 0; n < 9; ++n) {          // n==8: ones rows -> l accumulation
        int d = n * 16 + lrow;
        s8v vf = *(const s8v*)&Vs[d * 64 + ((tt * 32 + kq * 8) ^ ((d & 7) << 3))];
        MFMA16(acc_o[n], pa, vf);
      }
    }
  };

  stage_k(0, 0);
  int cur = 0;
  for (int kv = 0; kv <= qtB; ++kv) {
    const bool actA = (kv <= qtA);
    __syncthreads();
    if (kv < qtB) stage_k(cur ^ 1, kv + 1);
    stage_v(kv);

    f4v sB[4] = {}, sA[4] = {};
    if (actA) {
#pragma unroll
      for (int tt = 0; tt < 4; ++tt)
#pragma unroll
        for (int n = 0; n < 4; ++n) {
          int row = n * 16 + lrow;
          s8v kf = *(const s8v*)&Ks[cur][row * 128 + ((tt * 32 + kq * 8) ^ ((row & 7) << 3))];
          MFMA16(sB[n], kf, qfB[tt]);
          MFMA16(sA[n], kf, qfA[tt]);
        }
    } else {
#pragma unroll
      for (int tt = 0; tt < 4; ++tt)
#pragma unroll
        for (int n = 0; n < 4; ++n) {
          int row = n * 16 + lrow;
          s8v kf = *(const s8v*)&Ks[cur][row * 128 + ((tt * 32 + kq * 8) ^ ((row & 7) << 3))];
          MFMA16(sB[n], kf, qfB[tt]);
        }
    }
    __syncthreads();

    soft_pv(sB, qtB, kv, oB, mB);
    if (actA) soft_pv(sA, qtA, kv, oA, mA);
    cur ^= 1;
  }

#pragma unroll
  for (int n = 0; n < 8; ++n)
#pragma unroll
    for (int j = 0; j < 4; ++j) {
      int d = n * 16 + lrow;
      int qiB = qtB * 64 + wave * 16 + kq * 4 + j;
      O[(size_t)qiB * QD + h * HDIM + d] = __float2bfloat16(oB[n][j] / oB[8][j]);
      int qiA = qtA * 64 + wave * 16 + kq * 4 + j;
      O[(size_t)qiA * QD + h * HDIM + d] = __float2bfloat16(oA[n][j] / oA[8][j]);
    }
}

// ---------------- launch ----------------
extern "C" void kernel_launch(void* const* d_in, const int* in_sizes, int n_in,
                              void* d_out, int out_size, void* d_ws, size_t ws_size,
                              hipStream_t stream) {
  const float* x  = (const float*)d_in[0];
  const float* fc = (const float*)d_in[1];
  const float* fs = (const float*)d_in[2];
  const float* wq = (const float*)d_in[3];
  const float* wk = (const float*)d_in[4];
  const float* wv = (const float*)d_in[5];
  const float* wo = (const float*)d_in[6];
  float* out = (float*)d_out;

  char* ws = (char*)d_ws;
  auto alloc = [&](size_t bytes) {
    char* p = ws;
    ws += (bytes + 255) & ~(size_t)255;
    return p;
  };
  __hip_bfloat16* xb  = (__hip_bfloat16*)alloc((size_t)SEQ * DMODEL * 2);
  __hip_bfloat16* wf  = (__hip_bfloat16*)alloc((size_t)QKVN * DMODEL * 2);
  __hip_bfloat16* wob = (__hip_bfloat16*)alloc((size_t)DMODEL * QD * 2);
  __hip_bfloat16* Qb  = (__hip_bfloat16*)alloc((size_t)SEQ * QD * 2);
  __hip_bfloat16* Kc  = (__hip_bfloat16*)alloc((size_t)SEQ * KVD * 2);
  __hip_bfloat16* Vtg = (__hip_bfloat16*)alloc((size_t)KVD * SEQ * 2);
  __hip_bfloat16* Ob  = (__hip_bfloat16*)alloc((size_t)SEQ * QD * 2);
  float2*         fp  = (float2*)alloc((size_t)SEQ * 64 * 8);

  // 6291456 cvt units + 16384 pack units = 6307840 -> 24640 blocks
  k_cvt5<<<dim3(24640), dim3(256), 0, stream>>>(x, wq, wk, wv, wo, fc, fs, xb, wf, wob, fp);

  k_qkv<<<dim3(256), dim3(512), 0, stream>>>(xb, wf, fp, Qb, Kc, Vtg);

  k_flash<<<dim3(16, NH), 256, 0, stream>>>(Qb, Kc, Vtg, Ob);

  k_oproj<<<dim3(DMODEL / 256, SEQ / 128), dim3(512), 0, stream>>>(Ob, wob, out);
}

// Round 19
// 264.592 us; speedup vs baseline: 1.0161x; 1.0161x over previous
//
#include <hip/hip_runtime.h>
#include <hip/hip_bf16.h>
#include <stdint.h>

#define SEQ    2048
#define DMODEL 4096
#define NH     32
#define NKVH   8
#define HDIM   128
#define KVD    (NKVH*HDIM)   // 1024
#define QD     (NH*HDIM)     // 4096
#define QKVN   (QD + 2*KVD)  // 6144 fused projection columns
#define ASCALE 0.08838834764831845f

typedef __attribute__((ext_vector_type(8))) short s8v;   // 8 bf16
typedef __attribute__((ext_vector_type(4))) short s4v;   // 4 bf16
typedef __attribute__((ext_vector_type(4))) float f4v;   // 4 f32

#define MFMA16(acc, a, b) \
  asm("v_mfma_f32_16x16x32_bf16 %0, %1, %2, %0" : "+v"(acc) : "v"(a), "v"(b))

// full phase fence: order-pin + runtime barrier
#define SBAR() do { __builtin_amdgcn_sched_barrier(0); \
                    __builtin_amdgcn_s_barrier();      \
                    __builtin_amdgcn_sched_barrier(0); } while (0)
// pacing-only fence: preserves the compile-time interleave, no runtime sync
#define SFENCE() __builtin_amdgcn_sched_barrier(0)

__device__ __forceinline__ void gl2lds16(const void* g, void* l) {
  __builtin_amdgcn_global_load_lds(
      (const __attribute__((address_space(1))) void*)g,
      (__attribute__((address_space(3))) void*)l, 16, 0, 0);
}

// ---------------- merged f32 -> bf16 convert + fc/fs float2 pack (one launch) ----------------
__global__ __launch_bounds__(256) void k_cvt5(const float* __restrict__ x,
                                              const float* __restrict__ wq,
                                              const float* __restrict__ wk,
                                              const float* __restrict__ wv,
                                              const float* __restrict__ wo,
                                              const float* __restrict__ fc,
                                              const float* __restrict__ fs,
                                              __hip_bfloat16* __restrict__ xb,
                                              __hip_bfloat16* __restrict__ wf,
                                              __hip_bfloat16* __restrict__ wob,
                                              float2* __restrict__ fcs2) {
  int i = blockIdx.x * 256 + threadIdx.x;
  if (i >= 6291456) {                      // region 6: pack cos/sin interleaved (f32 copy)
    int j = i - 6291456;                   // 0..16383, 8 pairs each
    const float4* pc = (const float4*)fc + (size_t)j * 2;
    const float4* ps = (const float4*)fs + (size_t)j * 2;
    float4 c0 = pc[0], c1 = pc[1], s0 = ps[0], s1 = ps[1];
    float2* o = fcs2 + (size_t)j * 8;
    o[0] = {c0.x, s0.x}; o[1] = {c0.y, s0.y}; o[2] = {c0.z, s0.z}; o[3] = {c0.w, s0.w};
    o[4] = {c1.x, s1.x}; o[5] = {c1.y, s1.y}; o[6] = {c1.z, s1.z}; o[7] = {c1.w, s1.w};
    return;
  }
  const float* src;
  __hip_bfloat16* dst;
  float scale = 1.0f;
  if (i < 1048576)       { src = x;  dst = xb; }
  else if (i < 3145728)  { src = wq; dst = wf;  i -= 1048576; scale = ASCALE; }
  else if (i < 3670016)  { src = wk; dst = wf + (size_t)QD * DMODEL;  i -= 3145728; }
  else if (i < 4194304)  { src = wv; dst = wf + (size_t)(QD + KVD) * DMODEL; i -= 3670016; }
  else                   { src = wo; dst = wob; i -= 4194304; }
  const float4* p = (const float4*)src + (size_t)i * 2;
  float4 a = p[0], b = p[1];
  union { __hip_bfloat16 h[8]; s8v v; } o;
  o.h[0] = __float2bfloat16(a.x * scale); o.h[1] = __float2bfloat16(a.y * scale);
  o.h[2] = __float2bfloat16(a.z * scale); o.h[3] = __float2bfloat16(a.w * scale);
  o.h[4] = __float2bfloat16(b.x * scale); o.h[5] = __float2bfloat16(b.y * scale);
  o.h[6] = __float2bfloat16(b.z * scale); o.h[7] = __float2bfloat16(b.w * scale);
  *(s8v*)(dst + (size_t)i * 8) = o.v;
}

// ---------------- fused QKV projection: 4-phase, 4Mx2N waves, fused RoPE ----------------
// Barriers: boundary (vmcnt(7)+s_barrier, stages landed) and post-ph2 (reads of buf p
// done before ph3/ph4 overwrite). ph1/ph3 fences are pacing-only (SFENCE).
// R15-verified configuration (best measured: 264.7 us total).
__global__ __launch_bounds__(512, 2) void k_qkv(const __hip_bfloat16* __restrict__ A,
                                                const __hip_bfloat16* __restrict__ W,
                                                const float2* __restrict__ fcs2,
                                                __hip_bfloat16* __restrict__ Qb,
                                                __hip_bfloat16* __restrict__ Kc,
                                                __hip_bfloat16* __restrict__ Vt) {
  __shared__ __align__(16) __hip_bfloat16 sm[2][256 * 64 + 192 * 64];
  const int t5 = threadIdx.x;
  const int wave = t5 >> 6, lane = t5 & 63;
  const int lrow = lane & 15, kq = lane >> 4;
  const int wm = wave >> 1, wn = wave & 1;          // 4M x 2N
  const int mt = blockIdx.x & 7, nt = blockIdx.x >> 3;
  const int m0 = mt * 256, n0 = nt * 192;

  auto stageA = [&](int p, int kt) {
#pragma unroll
    for (int it = 0; it < 4; ++it) {
      int chunk = it * 512 + t5;
      int r = chunk >> 3, cc = ((chunk & 7) ^ (r & 7)) * 8;
      gl2lds16(A + (size_t)(m0 + r) * DMODEL + kt * 64 + cc,
               (char*)&sm[p][0] + it * 8192 + wave * 1024);
    }
  };
  auto stageB = [&](int p, int kt) {
#pragma unroll
    for (int it = 0; it < 3; ++it) {
      int chunk = it * 512 + t5;
      int r = chunk >> 3, cc = ((chunk & 7) ^ (r & 7)) * 8;
      gl2lds16(W + (size_t)(n0 + r) * DMODEL + kt * 64 + cc,
               (char*)&sm[p][0] + 32768 + it * 8192 + wave * 1024);
    }
  };

  f4v acc[4][6] = {};

  stageA(0, 0); stageB(0, 0);
  stageA(1, 1); stageB(1, 1);

  const int NT = DMODEL / 64;
#pragma unroll 2
  for (int t = 0; t < NT; ++t) {
    const int p = t & 1;
    const __hip_bfloat16* As = &sm[p][0];
    const __hip_bfloat16* Bs = &sm[p][256 * 64];

    __builtin_amdgcn_sched_barrier(0);
    if (t == NT - 1) asm volatile("s_waitcnt vmcnt(0)" ::: "memory");
    else             asm volatile("s_waitcnt vmcnt(7)" ::: "memory");
    __builtin_amdgcn_s_barrier();
    __builtin_amdgcn_sched_barrier(0);

    // ph1: read k0 frags (10), MFMA k0 x m0-1 (12)
    s8v a0[4], b0[6];
#pragma unroll
    for (int m = 0; m < 4; ++m) {
      int row = wm * 64 + m * 16 + lrow;
      a0[m] = *(const s8v*)&As[row * 64 + ((kq * 8) ^ ((row & 7) << 3))];
    }
#pragma unroll
    for (int n = 0; n < 6; ++n) {
      int row = wn * 96 + n * 16 + lrow;
      b0[n] = *(const s8v*)&Bs[row * 64 + ((kq * 8) ^ ((row & 7) << 3))];
    }
    __builtin_amdgcn_s_setprio(1);
#pragma unroll
    for (int m = 0; m < 2; ++m)
#pragma unroll
      for (int n = 0; n < 6; ++n) MFMA16(acc[m][n], a0[m], b0[n]);
    __builtin_amdgcn_s_setprio(0);
    SFENCE();                                   // pacing only

    // ph2: read k1 frags (10), MFMA k0 x m2-3 (12)
    s8v a1[4], b1[6];
#pragma unroll
    for (int m = 0; m < 4; ++m) {
      int row = wm * 64 + m * 16 + lrow;
      a1[m] = *(const s8v*)&As[row * 64 + ((32 + kq * 8) ^ ((row & 7) << 3))];
    }
#pragma unroll
    for (int n = 0; n < 6; ++n) {
      int row = wn * 96 + n * 16 + lrow;
      b1[n] = *(const s8v*)&Bs[row * 64 + ((32 + kq * 8) ^ ((row & 7) << 3))];
    }
    __builtin_amdgcn_s_setprio(1);
#pragma unroll
    for (int m = 2; m < 4; ++m)
#pragma unroll
      for (int n = 0; n < 6; ++n) MFMA16(acc[m][n], a0[m], b0[n]);
    __builtin_amdgcn_s_setprio(0);
    SBAR();   // correctness: all reads of buf p complete -> safe to overwrite

    // ph3: stage A(t+2), MFMA k1 x m0-1
    if (t + 2 < NT) stageA(p, t + 2);
    __builtin_amdgcn_s_setprio(1);
#pragma unroll
    for (int m = 0; m < 2; ++m)
#pragma unroll
      for (int n = 0; n < 6; ++n) MFMA16(acc[m][n], a1[m], b1[n]);
    __builtin_amdgcn_s_setprio(0);
    SFENCE();                                   // pacing only

    // ph4: stage B(t+2), MFMA k1 x m2-3
    if (t + 2 < NT) stageB(p, t + 2);
    __builtin_amdgcn_s_setprio(1);
#pragma unroll
    for (int m = 2; m < 4; ++m)
#pragma unroll
      for (int n = 0; n < 6; ++n) MFMA16(acc[m][n], a1[m], b1[n]);
    __builtin_amdgcn_s_setprio(0);
  }

  // epilogue: Q/K fused rope (float2 cos/sin); V transposed
#pragma unroll
  for (int m = 0; m < 4; ++m)
#pragma unroll
    for (int n = 0; n < 6; ++n) {
      int c = n0 + wn * 96 + n * 16 + lrow;
      int r0 = m0 + wm * 64 + m * 16 + kq * 4;
      if (c < QD + KVD) {
        const int ii = (c & 127) >> 1;
        const bool odd = c & 1;
        float vout[4];
#pragma unroll
        for (int j = 0; j < 4; ++j) {
          float v = acc[m][n][j];
          float pvt = __shfl_xor(v, 1, 64);
          float2 cs = fcs2[(size_t)(r0 + j) * 64 + ii];
          vout[j] = odd ? (pvt * cs.y + v * cs.x) : (v * cs.x - pvt * cs.y);
        }
        if (c < QD) {
#pragma unroll
          for (int j = 0; j < 4; ++j)
            Qb[(size_t)(r0 + j) * QD + c] = __float2bfloat16(vout[j]);
        } else {
#pragma unroll
          for (int j = 0; j < 4; ++j)
            Kc[(size_t)(r0 + j) * KVD + (c - QD)] = __float2bfloat16(vout[j]);
        }
      } else {
        union { __hip_bfloat16 b[4]; s4v v; } u;
#pragma unroll
        for (int j = 0; j < 4; ++j) u.b[j] = __float2bfloat16(acc[m][n][j]);
        *(s4v*)&Vt[(size_t)(c - QD - KVD) * SEQ + r0] = u.v;
      }
    }
}

// ---------------- O-projection: 4-phase counted-vmcnt 128x256, pacing fences relaxed ----------------
__global__ __launch_bounds__(512, 2) void k_oproj(const __hip_bfloat16* __restrict__ A,
                                                  const __hip_bfloat16* __restrict__ B,
                                                  float* __restrict__ C) {
  __shared__ __align__(16) __hip_bfloat16 sm[2][128 * 64 + 256 * 64];
  const int t5 = threadIdx.x;
  const int wave = t5 >> 6, lane = t5 & 63;
  const int lrow = lane & 15, kq = lane >> 4;
  const int wm = wave >> 2, wn = wave & 3;
  const int m0 = blockIdx.y * 128, n0 = blockIdx.x * 256;

  auto stageA = [&](int p, int kt) {
#pragma unroll
    for (int it = 0; it < 2; ++it) {
      int chunk = it * 512 + t5;
      int r = chunk >> 3, cc = ((chunk & 7) ^ (r & 7)) * 8;
      gl2lds16(A + (size_t)(m0 + r) * QD + kt * 64 + cc,
               (char*)&sm[p][0] + it * 8192 + wave * 1024);
    }
  };
  auto stageB = [&](int p, int kt) {
#pragma unroll
    for (int it = 0; it < 4; ++it) {
      int chunk = it * 512 + t5;
      int r = chunk >> 3, cc = ((chunk & 7) ^ (r & 7)) * 8;
      gl2lds16(B + (size_t)(n0 + r) * QD + kt * 64 + cc,
               (char*)&sm[p][0] + 16384 + it * 8192 + wave * 1024);
    }
  };

  f4v acc[4][4] = {};

  stageA(0, 0); stageB(0, 0);
  stageA(1, 1); stageB(1, 1);

  const int NT = QD / 64;
#pragma unroll 2
  for (int t = 0; t < NT; ++t) {
    const int p = t & 1;
    const __hip_bfloat16* As = &sm[p][0];
    const __hip_bfloat16* Bs = &sm[p][128 * 64];

    __builtin_amdgcn_sched_barrier(0);
    if (t == NT - 1) asm volatile("s_waitcnt vmcnt(0)" ::: "memory");
    else             asm volatile("s_waitcnt vmcnt(6)" ::: "memory");
    __builtin_amdgcn_s_barrier();
    __builtin_amdgcn_sched_barrier(0);

    s8v a0[4], b0[4];
#pragma unroll
    for (int m = 0; m < 4; ++m) {
      int row = wm * 64 + m * 16 + lrow;
      a0[m] = *(const s8v*)&As[row * 64 + ((kq * 8) ^ ((row & 7) << 3))];
    }
#pragma unroll
    for (int n = 0; n < 4; ++n) {
      int row = wn * 64 + n * 16 + lrow;
      b0[n] = *(const s8v*)&Bs[row * 64 + ((kq * 8) ^ ((row & 7) << 3))];
    }
    __builtin_amdgcn_s_setprio(1);
#pragma unroll
    for (int m = 0; m < 2; ++m)
#pragma unroll
      for (int n = 0; n < 4; ++n) MFMA16(acc[m][n], a0[m], b0[n]);
    __builtin_amdgcn_s_setprio(0);
    SFENCE();                                   // pacing only

    s8v a1[4], b1[4];
#pragma unroll
    for (int m = 0; m < 4; ++m) {
      int row = wm * 64 + m * 16 + lrow;
      a1[m] = *(const s8v*)&As[row * 64 + ((32 + kq * 8) ^ ((row & 7) << 3))];
    }
#pragma unroll
    for (int n = 0; n < 4; ++n) {
      int row = wn * 64 + n * 16 + lrow;
      b1[n] = *(const s8v*)&Bs[row * 64 + ((32 + kq * 8) ^ ((row & 7) << 3))];
    }
    __builtin_amdgcn_s_setprio(1);
#pragma unroll
    for (int m = 2; m < 4; ++m)
#pragma unroll
      for (int n = 0; n < 4; ++n) MFMA16(acc[m][n], a0[m], b0[n]);
    __builtin_amdgcn_s_setprio(0);
    SBAR();   // correctness: reads of buf p done before overwrite

    if (t + 2 < NT) stageA(p, t + 2);
    __builtin_amdgcn_s_setprio(1);
#pragma unroll
    for (int m = 0; m < 2; ++m)
#pragma unroll
      for (int n = 0; n < 4; ++n) MFMA16(acc[m][n], a1[m], b1[n]);
    __builtin_amdgcn_s_setprio(0);
    SFENCE();                                   // pacing only

    if (t + 2 < NT) stageB(p, t + 2);
    __builtin_amdgcn_s_setprio(1);
#pragma unroll
    for (int m = 2; m < 4; ++m)
#pragma unroll
      for (int n = 0; n < 4; ++n) MFMA16(acc[m][n], a1[m], b1[n]);
    __builtin_amdgcn_s_setprio(0);
  }

#pragma unroll
  for (int m = 0; m < 4; ++m)
#pragma unroll
    for (int n = 0; n < 4; ++n)
#pragma unroll
      for (int j = 0; j < 4; ++j) {
        int r = m0 + wm * 64 + m * 16 + kq * 4 + j;
        int c = n0 + wn * 64 + n * 16 + lrow;
        C[(size_t)r * DMODEL + c] = acc[m][n][j];
      }
}

// ---------------- causal flash attention: R13 verified form (FINAL) ----------------
__global__ __launch_bounds__(256, 2) void k_flash(const __hip_bfloat16* __restrict__ Q,
                                                  const __hip_bfloat16* __restrict__ Kb,
                                                  const __hip_bfloat16* __restrict__ Vtg,
                                                  __hip_bfloat16* __restrict__ O) {
  __shared__ __align__(16) __hip_bfloat16 Ks[2][64 * 128];
  __shared__ __align__(16) __hip_bfloat16 Vs[144 * 64];   // rows 128..143 = ones
  __shared__ __align__(16) __hip_bfloat16 Ps[4][16 * 64];
  const int qp = blockIdx.x, h = blockIdx.y, g = h >> 2;
  const int t = threadIdx.x, wave = t >> 6, lane = t & 63;
  const int lrow = lane & 15, kq = lane >> 4;
  const int qtA = qp, qtB = 31 - qp;

  s8v qfA[4], qfB[4];
  {
    const int qrA = qtA * 64 + wave * 16 + lrow;
    const int qrB = qtB * 64 + wave * 16 + lrow;
#pragma unroll
    for (int tt = 0; tt < 4; ++tt) {
      qfA[tt] = *(const s8v*)(Q + (size_t)qrA * QD + h * HDIM + tt * 32 + kq * 8);
      qfB[tt] = *(const s8v*)(Q + (size_t)qrB * QD + h * HDIM + tt * 32 + kq * 8);
    }
  }

  if (t < 128) {
    union { __hip_bfloat16 h8[8]; s8v v; } one;
#pragma unroll
    for (int e = 0; e < 8; ++e) one.h8[e] = __float2bfloat16(1.0f);
    *(s8v*)&Vs[128 * 64 + t * 8] = one.v;
  }

  f4v oA[9] = {}, oB[9] = {};   // [8] = l accumulator (ones-column)
  float mA = -1e30f, mB = -1e30f;

  auto stage_k = [&](int buf, int kv) {
#pragma unroll
    for (int it = 0; it < 4; ++it) {
      int chunk = it * 256 + t;
      int r = chunk >> 4, cc = ((chunk & 15) ^ (r & 7)) * 8;
      gl2lds16(Kb + (size_t)(kv * 64 + r) * KVD + g * HDIM + cc,
               (char*)&Ks[buf][0] + it * 4096 + wave * 1024);
    }
  };
  auto stage_v = [&](int kv) {
#pragma unroll
    for (int it = 0; it < 4; ++it) {
      int chunk = it * 256 + t;
      int d = chunk >> 3, cc = ((chunk & 7) ^ (d & 7)) * 8;
      gl2lds16(Vtg + (size_t)(g * HDIM + d) * SEQ + kv * 64 + cc,
               (char*)Vs + it * 4096 + wave * 1024);
    }
  };

  auto soft_pv = [&](f4v (&s)[4], int qt, int kv, f4v (&acc_o)[9], float& mrun) {
    __hip_bfloat16* P = &Ps[wave][0];
    const bool diag = (kv == qt);
    const int qi = qt * 64 + wave * 16 + lrow;
    const int swz = (lrow & 7) << 3;
    float pv[4][4];
    float mx = -1e30f;
#pragma unroll
    for (int n = 0; n < 4; ++n)
#pragma unroll
      for (int j = 0; j < 4; ++j) {
        float v = s[n][j];
        if (diag) {
          int ki = kv * 64 + n * 16 + kq * 4 + j;
          if (ki > qi) v = -1e30f;
        }
        pv[n][j] = v;
        mx = fmaxf(mx, v);
      }
    mx = fmaxf(mx, __shfl_xor(mx, 16, 64));
    mx = fmaxf(mx, __shfl_xor(mx, 32, 64));
    if (!__all(mx <= mrun)) {
      float mnew = fmaxf(mrun, mx);
      float fsc = __expf(mrun - mnew);
      mrun = mnew;
      float fj[4];
#pragma unroll
      for (int j = 0; j < 4; ++j) fj[j] = __shfl(fsc, kq * 4 + j, 64);
#pragma unroll
      for (int n = 0; n < 9; ++n) {
        acc_o[n][0] *= fj[0]; acc_o[n][1] *= fj[1];
        acc_o[n][2] *= fj[2]; acc_o[n][3] *= fj[3];
      }
    }
    asm volatile("" ::: "memory");
#pragma unroll
    for (int n = 0; n < 4; ++n) {
      union { __hip_bfloat16 b[4]; s4v v; } u;
#pragma unroll
      for (int j = 0; j < 4; ++j) u.b[j] = __float2bfloat16(__expf(pv[n][j] - mrun));
      *(s4v*)&P[lrow * 64 + ((n * 16 + kq * 4) ^ swz)] = u.v;
    }
    asm volatile("" ::: "memory");
#pragma unroll
    for (int tt = 0; tt < 2; ++tt) {
      s8v pa = *(const s8v*)&P[lrow * 64 + ((tt * 32 + kq * 8) ^ swz)];
#pragma unroll
      for (int n = 0; n < 9; ++n) {          // n==8: ones rows -> l accumulation
        int d = n * 16 + lrow;
        s8v vf = *(const s8v*)&Vs[d * 64 + ((tt * 32 + kq * 8) ^ ((d & 7) << 3))];
        MFMA16(acc_o[n], pa, vf);
      }
    }
  };

  stage_k(0, 0);
  int cur = 0;
  for (int kv = 0; kv <= qtB; ++kv) {
    const bool actA = (kv <= qtA);
    __syncthreads();
    if (kv < qtB) stage_k(cur ^ 1, kv + 1);
    stage_v(kv);

    f4v sB[4] = {}, sA[4] = {};
    if (actA) {
#pragma unroll
      for (int tt = 0; tt < 4; ++tt)
#pragma unroll
        for (int n = 0; n < 4; ++n) {
          int row = n * 16 + lrow;
          s8v kf = *(const s8v*)&Ks[cur][row * 128 + ((tt * 32 + kq * 8) ^ ((row & 7) << 3))];
          MFMA16(sB[n], kf, qfB[tt]);
          MFMA16(sA[n], kf, qfA[tt]);
        }
    } else {
#pragma unroll
      for (int tt = 0; tt < 4; ++tt)
#pragma unroll
        for (int n = 0; n < 4; ++n) {
          int row = n * 16 + lrow;
          s8v kf = *(const s8v*)&Ks[cur][row * 128 + ((tt * 32 + kq * 8) ^ ((row & 7) << 3))];
          MFMA16(sB[n], kf, qfB[tt]);
        }
    }
    __syncthreads();

    soft_pv(sB, qtB, kv, oB, mB);
    if (actA) soft_pv(sA, qtA, kv, oA, mA);
    cur ^= 1;
  }

#pragma unroll
  for (int n = 0; n < 8; ++n)
#pragma unroll
    for (int j = 0; j < 4; ++j) {
      int d = n * 16 + lrow;
      int qiB = qtB * 64 + wave * 16 + kq * 4 + j;
      O[(size_t)qiB * QD + h * HDIM + d] = __float2bfloat16(oB[n][j] / oB[8][j]);
      int qiA = qtA * 64 + wave * 16 + kq * 4 + j;
      O[(size_t)qiA * QD + h * HDIM + d] = __float2bfloat16(oA[n][j] / oA[8][j]);
    }
}

// ---------------- launch ----------------
extern "C" void kernel_launch(void* const* d_in, const int* in_sizes, int n_in,
                              void* d_out, int out_size, void* d_ws, size_t ws_size,
                              hipStream_t stream) {
  const float* x  = (const float*)d_in[0];
  const float* fc = (const float*)d_in[1];
  const float* fs = (const float*)d_in[2];
  const float* wq = (const float*)d_in[3];
  const float* wk = (const float*)d_in[4];
  const float* wv = (const float*)d_in[5];
  const float* wo = (const float*)d_in[6];
  float* out = (float*)d_out;

  char* ws = (char*)d_ws;
  auto alloc = [&](size_t bytes) {
    char* p = ws;
    ws += (bytes + 255) & ~(size_t)255;
    return p;
  };
  __hip_bfloat16* xb  = (__hip_bfloat16*)alloc((size_t)SEQ * DMODEL * 2);
  __hip_bfloat16* wf  = (__hip_bfloat16*)alloc((size_t)QKVN * DMODEL * 2);
  __hip_bfloat16* wob = (__hip_bfloat16*)alloc((size_t)DMODEL * QD * 2);
  __hip_bfloat16* Qb  = (__hip_bfloat16*)alloc((size_t)SEQ * QD * 2);
  __hip_bfloat16* Kc  = (__hip_bfloat16*)alloc((size_t)SEQ * KVD * 2);
  __hip_bfloat16* Vtg = (__hip_bfloat16*)alloc((size_t)KVD * SEQ * 2);
  __hip_bfloat16* Ob  = (__hip_bfloat16*)alloc((size_t)SEQ * QD * 2);
  float2*         fp  = (float2*)alloc((size_t)SEQ * 64 * 8);

  // 6291456 cvt units + 16384 pack units = 6307840 -> 24640 blocks
  k_cvt5<<<dim3(24640), dim3(256), 0, stream>>>(x, wq, wk, wv, wo, fc, fs, xb, wf, wob, fp);

  k_qkv<<<dim3(256), dim3(512), 0, stream>>>(xb, wf, fp, Qb, Kc, Vtg);

  k_flash<<<dim3(16, NH), 256, 0, stream>>>(Qb, Kc, Vtg, Ob);

  k_oproj<<<dim3(DMODEL / 256, SEQ / 128), dim3(512), 0, stream>>>(Ob, wob, out);
}

// Round 20
// 264.590 us; speedup vs baseline: 1.0161x; 1.0000x over previous
//
#include <hip/hip_runtime.h>
#include <hip/hip_bf16.h>
#include <stdint.h>

#define SEQ    2048
#define DMODEL 4096
#define NH     32
#define NKVH   8
#define HDIM   128
#define KVD    (NKVH*HDIM)   // 1024
#define QD     (NH*HDIM)     // 4096
#define QKVN   (QD + 2*KVD)  // 6144 fused projection columns
#define ASCALE 0.08838834764831845f

typedef __attribute__((ext_vector_type(8))) short s8v;   // 8 bf16
typedef __attribute__((ext_vector_type(4))) short s4v;   // 4 bf16
typedef __attribute__((ext_vector_type(4))) float f4v;   // 4 f32

#define MFMA16(acc, a, b) \
  asm("v_mfma_f32_16x16x32_bf16 %0, %1, %2, %0" : "+v"(acc) : "v"(a), "v"(b))

// full phase fence: order-pin + runtime barrier
#define SBAR() do { __builtin_amdgcn_sched_barrier(0); \
                    __builtin_amdgcn_s_barrier();      \
                    __builtin_amdgcn_sched_barrier(0); } while (0)
// pacing-only fence: preserves the compile-time interleave, no runtime sync
#define SFENCE() __builtin_amdgcn_sched_barrier(0)

__device__ __forceinline__ void gl2lds16(const void* g, void* l) {
  __builtin_amdgcn_global_load_lds(
      (const __attribute__((address_space(1))) void*)g,
      (__attribute__((address_space(3))) void*)l, 16, 0, 0);
}

// ---------------- merged f32 -> bf16 convert + fc/fs float2 pack (one launch) ----------------
__global__ __launch_bounds__(256) void k_cvt5(const float* __restrict__ x,
                                              const float* __restrict__ wq,
                                              const float* __restrict__ wk,
                                              const float* __restrict__ wv,
                                              const float* __restrict__ wo,
                                              const float* __restrict__ fc,
                                              const float* __restrict__ fs,
                                              __hip_bfloat16* __restrict__ xb,
                                              __hip_bfloat16* __restrict__ wf,
                                              __hip_bfloat16* __restrict__ wob,
                                              float2* __restrict__ fcs2) {
  int i = blockIdx.x * 256 + threadIdx.x;
  if (i >= 6291456) {                      // region 6: pack cos/sin interleaved (f32 copy)
    int j = i - 6291456;                   // 0..16383, 8 pairs each
    const float4* pc = (const float4*)fc + (size_t)j * 2;
    const float4* ps = (const float4*)fs + (size_t)j * 2;
    float4 c0 = pc[0], c1 = pc[1], s0 = ps[0], s1 = ps[1];
    float2* o = fcs2 + (size_t)j * 8;
    o[0] = {c0.x, s0.x}; o[1] = {c0.y, s0.y}; o[2] = {c0.z, s0.z}; o[3] = {c0.w, s0.w};
    o[4] = {c1.x, s1.x}; o[5] = {c1.y, s1.y}; o[6] = {c1.z, s1.z}; o[7] = {c1.w, s1.w};
    return;
  }
  const float* src;
  __hip_bfloat16* dst;
  float scale = 1.0f;
  if (i < 1048576)       { src = x;  dst = xb; }
  else if (i < 3145728)  { src = wq; dst = wf;  i -= 1048576; scale = ASCALE; }
  else if (i < 3670016)  { src = wk; dst = wf + (size_t)QD * DMODEL;  i -= 3145728; }
  else if (i < 4194304)  { src = wv; dst = wf + (size_t)(QD + KVD) * DMODEL; i -= 3670016; }
  else                   { src = wo; dst = wob; i -= 4194304; }
  const float4* p = (const float4*)src + (size_t)i * 2;
  float4 a = p[0], b = p[1];
  union { __hip_bfloat16 h[8]; s8v v; } o;
  o.h[0] = __float2bfloat16(a.x * scale); o.h[1] = __float2bfloat16(a.y * scale);
  o.h[2] = __float2bfloat16(a.z * scale); o.h[3] = __float2bfloat16(a.w * scale);
  o.h[4] = __float2bfloat16(b.x * scale); o.h[5] = __float2bfloat16(b.y * scale);
  o.h[6] = __float2bfloat16(b.z * scale); o.h[7] = __float2bfloat16(b.w * scale);
  *(s8v*)(dst + (size_t)i * 8) = o.v;
}

// ---------------- fused QKV projection: 4-phase, 4Mx2N waves, fused RoPE ----------------
// Barriers: boundary (vmcnt(7)+s_barrier, stages landed) and post-ph2 (reads of buf p
// done before ph3/ph4 overwrite). ph1/ph3 fences are pacing-only (SFENCE).
// R15-verified configuration (best measured: 264.7 us total).
__global__ __launch_bounds__(512, 2) void k_qkv(const __hip_bfloat16* __restrict__ A,
                                                const __hip_bfloat16* __restrict__ W,
                                                const float2* __restrict__ fcs2,
                                                __hip_bfloat16* __restrict__ Qb,
                                                __hip_bfloat16* __restrict__ Kc,
                                                __hip_bfloat16* __restrict__ Vt) {
  __shared__ __align__(16) __hip_bfloat16 sm[2][256 * 64 + 192 * 64];
  const int t5 = threadIdx.x;
  const int wave = t5 >> 6, lane = t5 & 63;
  const int lrow = lane & 15, kq = lane >> 4;
  const int wm = wave >> 1, wn = wave & 1;          // 4M x 2N
  const int mt = blockIdx.x & 7, nt = blockIdx.x >> 3;
  const int m0 = mt * 256, n0 = nt * 192;

  auto stageA = [&](int p, int kt) {
#pragma unroll
    for (int it = 0; it < 4; ++it) {
      int chunk = it * 512 + t5;
      int r = chunk >> 3, cc = ((chunk & 7) ^ (r & 7)) * 8;
      gl2lds16(A + (size_t)(m0 + r) * DMODEL + kt * 64 + cc,
               (char*)&sm[p][0] + it * 8192 + wave * 1024);
    }
  };
  auto stageB = [&](int p, int kt) {
#pragma unroll
    for (int it = 0; it < 3; ++it) {
      int chunk = it * 512 + t5;
      int r = chunk >> 3, cc = ((chunk & 7) ^ (r & 7)) * 8;
      gl2lds16(W + (size_t)(n0 + r) * DMODEL + kt * 64 + cc,
               (char*)&sm[p][0] + 32768 + it * 8192 + wave * 1024);
    }
  };

  f4v acc[4][6] = {};

  stageA(0, 0); stageB(0, 0);
  stageA(1, 1); stageB(1, 1);

  const int NT = DMODEL / 64;
#pragma unroll 2
  for (int t = 0; t < NT; ++t) {
    const int p = t & 1;
    const __hip_bfloat16* As = &sm[p][0];
    const __hip_bfloat16* Bs = &sm[p][256 * 64];

    __builtin_amdgcn_sched_barrier(0);
    if (t == NT - 1) asm volatile("s_waitcnt vmcnt(0)" ::: "memory");
    else             asm volatile("s_waitcnt vmcnt(7)" ::: "memory");
    __builtin_amdgcn_s_barrier();
    __builtin_amdgcn_sched_barrier(0);

    // ph1: read k0 frags (10), MFMA k0 x m0-1 (12)
    s8v a0[4], b0[6];
#pragma unroll
    for (int m = 0; m < 4; ++m) {
      int row = wm * 64 + m * 16 + lrow;
      a0[m] = *(const s8v*)&As[row * 64 + ((kq * 8) ^ ((row & 7) << 3))];
    }
#pragma unroll
    for (int n = 0; n < 6; ++n) {
      int row = wn * 96 + n * 16 + lrow;
      b0[n] = *(const s8v*)&Bs[row * 64 + ((kq * 8) ^ ((row & 7) << 3))];
    }
    __builtin_amdgcn_s_setprio(1);
#pragma unroll
    for (int m = 0; m < 2; ++m)
#pragma unroll
      for (int n = 0; n < 6; ++n) MFMA16(acc[m][n], a0[m], b0[n]);
    __builtin_amdgcn_s_setprio(0);
    SFENCE();                                   // pacing only

    // ph2: read k1 frags (10), MFMA k0 x m2-3 (12)
    s8v a1[4], b1[6];
#pragma unroll
    for (int m = 0; m < 4; ++m) {
      int row = wm * 64 + m * 16 + lrow;
      a1[m] = *(const s8v*)&As[row * 64 + ((32 + kq * 8) ^ ((row & 7) << 3))];
    }
#pragma unroll
    for (int n = 0; n < 6; ++n) {
      int row = wn * 96 + n * 16 + lrow;
      b1[n] = *(const s8v*)&Bs[row * 64 + ((32 + kq * 8) ^ ((row & 7) << 3))];
    }
    __builtin_amdgcn_s_setprio(1);
#pragma unroll
    for (int m = 2; m < 4; ++m)
#pragma unroll
      for (int n = 0; n < 6; ++n) MFMA16(acc[m][n], a0[m], b0[n]);
    __builtin_amdgcn_s_setprio(0);
    SBAR();   // correctness: all reads of buf p complete -> safe to overwrite

    // ph3: stage A(t+2), MFMA k1 x m0-1
    if (t + 2 < NT) stageA(p, t + 2);
    __builtin_amdgcn_s_setprio(1);
#pragma unroll
    for (int m = 0; m < 2; ++m)
#pragma unroll
      for (int n = 0; n < 6; ++n) MFMA16(acc[m][n], a1[m], b1[n]);
    __builtin_amdgcn_s_setprio(0);
    SFENCE();                                   // pacing only

    // ph4: stage B(t+2), MFMA k1 x m2-3
    if (t + 2 < NT) stageB(p, t + 2);
    __builtin_amdgcn_s_setprio(1);
#pragma unroll
    for (int m = 2; m < 4; ++m)
#pragma unroll
      for (int n = 0; n < 6; ++n) MFMA16(acc[m][n], a1[m], b1[n]);
    __builtin_amdgcn_s_setprio(0);
  }

  // epilogue: Q/K fused rope (float2 cos/sin); V transposed
#pragma unroll
  for (int m = 0; m < 4; ++m)
#pragma unroll
    for (int n = 0; n < 6; ++n) {
      int c = n0 + wn * 96 + n * 16 + lrow;
      int r0 = m0 + wm * 64 + m * 16 + kq * 4;
      if (c < QD + KVD) {
        const int ii = (c & 127) >> 1;
        const bool odd = c & 1;
        float vout[4];
#pragma unroll
        for (int j = 0; j < 4; ++j) {
          float v = acc[m][n][j];
          float pvt = __shfl_xor(v, 1, 64);
          float2 cs = fcs2[(size_t)(r0 + j) * 64 + ii];
          vout[j] = odd ? (pvt * cs.y + v * cs.x) : (v * cs.x - pvt * cs.y);
        }
        if (c < QD) {
#pragma unroll
          for (int j = 0; j < 4; ++j)
            Qb[(size_t)(r0 + j) * QD + c] = __float2bfloat16(vout[j]);
        } else {
#pragma unroll
          for (int j = 0; j < 4; ++j)
            Kc[(size_t)(r0 + j) * KVD + (c - QD)] = __float2bfloat16(vout[j]);
        }
      } else {
        union { __hip_bfloat16 b[4]; s4v v; } u;
#pragma unroll
        for (int j = 0; j < 4; ++j) u.b[j] = __float2bfloat16(acc[m][n][j]);
        *(s4v*)&Vt[(size_t)(c - QD - KVD) * SEQ + r0] = u.v;
      }
    }
}

// ---------------- O-projection: 4-phase counted-vmcnt 128x256, pacing fences relaxed ----------------
__global__ __launch_bounds__(512, 2) void k_oproj(const __hip_bfloat16* __restrict__ A,
                                                  const __hip_bfloat16* __restrict__ B,
                                                  float* __restrict__ C) {
  __shared__ __align__(16) __hip_bfloat16 sm[2][128 * 64 + 256 * 64];
  const int t5 = threadIdx.x;
  const int wave = t5 >> 6, lane = t5 & 63;
  const int lrow = lane & 15, kq = lane >> 4;
  const int wm = wave >> 2, wn = wave & 3;
  const int m0 = blockIdx.y * 128, n0 = blockIdx.x * 256;

  auto stageA = [&](int p, int kt) {
#pragma unroll
    for (int it = 0; it < 2; ++it) {
      int chunk = it * 512 + t5;
      int r = chunk >> 3, cc = ((chunk & 7) ^ (r & 7)) * 8;
      gl2lds16(A + (size_t)(m0 + r) * QD + kt * 64 + cc,
               (char*)&sm[p][0] + it * 8192 + wave * 1024);
    }
  };
  auto stageB = [&](int p, int kt) {
#pragma unroll
    for (int it = 0; it < 4; ++it) {
      int chunk = it * 512 + t5;
      int r = chunk >> 3, cc = ((chunk & 7) ^ (r & 7)) * 8;
      gl2lds16(B + (size_t)(n0 + r) * QD + kt * 64 + cc,
               (char*)&sm[p][0] + 16384 + it * 8192 + wave * 1024);
    }
  };

  f4v acc[4][4] = {};

  stageA(0, 0); stageB(0, 0);
  stageA(1, 1); stageB(1, 1);

  const int NT = QD / 64;
#pragma unroll 2
  for (int t = 0; t < NT; ++t) {
    const int p = t & 1;
    const __hip_bfloat16* As = &sm[p][0];
    const __hip_bfloat16* Bs = &sm[p][128 * 64];

    __builtin_amdgcn_sched_barrier(0);
    if (t == NT - 1) asm volatile("s_waitcnt vmcnt(0)" ::: "memory");
    else             asm volatile("s_waitcnt vmcnt(6)" ::: "memory");
    __builtin_amdgcn_s_barrier();
    __builtin_amdgcn_sched_barrier(0);

    s8v a0[4], b0[4];
#pragma unroll
    for (int m = 0; m < 4; ++m) {
      int row = wm * 64 + m * 16 + lrow;
      a0[m] = *(const s8v*)&As[row * 64 + ((kq * 8) ^ ((row & 7) << 3))];
    }
#pragma unroll
    for (int n = 0; n < 4; ++n) {
      int row = wn * 64 + n * 16 + lrow;
      b0[n] = *(const s8v*)&Bs[row * 64 + ((kq * 8) ^ ((row & 7) << 3))];
    }
    __builtin_amdgcn_s_setprio(1);
#pragma unroll
    for (int m = 0; m < 2; ++m)
#pragma unroll
      for (int n = 0; n < 4; ++n) MFMA16(acc[m][n], a0[m], b0[n]);
    __builtin_amdgcn_s_setprio(0);
    SFENCE();                                   // pacing only

    s8v a1[4], b1[4];
#pragma unroll
    for (int m = 0; m < 4; ++m) {
      int row = wm * 64 + m * 16 + lrow;
      a1[m] = *(const s8v*)&As[row * 64 + ((32 + kq * 8) ^ ((row & 7) << 3))];
    }
#pragma unroll
    for (int n = 0; n < 4; ++n) {
      int row = wn * 64 + n * 16 + lrow;
      b1[n] = *(const s8v*)&Bs[row * 64 + ((32 + kq * 8) ^ ((row & 7) << 3))];
    }
    __builtin_amdgcn_s_setprio(1);
#pragma unroll
    for (int m = 2; m < 4; ++m)
#pragma unroll
      for (int n = 0; n < 4; ++n) MFMA16(acc[m][n], a0[m], b0[n]);
    __builtin_amdgcn_s_setprio(0);
    SBAR();   // correctness: reads of buf p done before overwrite

    if (t + 2 < NT) stageA(p, t + 2);
    __builtin_amdgcn_s_setprio(1);
#pragma unroll
    for (int m = 0; m < 2; ++m)
#pragma unroll
      for (int n = 0; n < 4; ++n) MFMA16(acc[m][n], a1[m], b1[n]);
    __builtin_amdgcn_s_setprio(0);
    SFENCE();                                   // pacing only

    if (t + 2 < NT) stageB(p, t + 2);
    __builtin_amdgcn_s_setprio(1);
#pragma unroll
    for (int m = 2; m < 4; ++m)
#pragma unroll
      for (int n = 0; n < 4; ++n) MFMA16(acc[m][n], a1[m], b1[n]);
    __builtin_amdgcn_s_setprio(0);
  }

#pragma unroll
  for (int m = 0; m < 4; ++m)
#pragma unroll
    for (int n = 0; n < 4; ++n)
#pragma unroll
      for (int j = 0; j < 4; ++j) {
        int r = m0 + wm * 64 + m * 16 + kq * 4 + j;
        int c = n0 + wn * 64 + n * 16 + lrow;
        C[(size_t)r * DMODEL + c] = acc[m][n][j];
      }
}

// ---------------- causal flash attention: R13 verified form (FINAL) ----------------
__global__ __launch_bounds__(256, 2) void k_flash(const __hip_bfloat16* __restrict__ Q,
                                                  const __hip_bfloat16* __restrict__ Kb,
                                                  const __hip_bfloat16* __restrict__ Vtg,
                                                  __hip_bfloat16* __restrict__ O) {
  __shared__ __align__(16) __hip_bfloat16 Ks[2][64 * 128];
  __shared__ __align__(16) __hip_bfloat16 Vs[144 * 64];   // rows 128..143 = ones
  __shared__ __align__(16) __hip_bfloat16 Ps[4][16 * 64];
  const int qp = blockIdx.x, h = blockIdx.y, g = h >> 2;
  const int t = threadIdx.x, wave = t >> 6, lane = t & 63;
  const int lrow = lane & 15, kq = lane >> 4;
  const int qtA = qp, qtB = 31 - qp;

  s8v qfA[4], qfB[4];
  {
    const int qrA = qtA * 64 + wave * 16 + lrow;
    const int qrB = qtB * 64 + wave * 16 + lrow;
#pragma unroll
    for (int tt = 0; tt < 4; ++tt) {
      qfA[tt] = *(const s8v*)(Q + (size_t)qrA * QD + h * HDIM + tt * 32 + kq * 8);
      qfB[tt] = *(const s8v*)(Q + (size_t)qrB * QD + h * HDIM + tt * 32 + kq * 8);
    }
  }

  if (t < 128) {
    union { __hip_bfloat16 h8[8]; s8v v; } one;
#pragma unroll
    for (int e = 0; e < 8; ++e) one.h8[e] = __float2bfloat16(1.0f);
    *(s8v*)&Vs[128 * 64 + t * 8] = one.v;
  }

  f4v oA[9] = {}, oB[9] = {};   // [8] = l accumulator (ones-column)
  float mA = -1e30f, mB = -1e30f;

  auto stage_k = [&](int buf, int kv) {
#pragma unroll
    for (int it = 0; it < 4; ++it) {
      int chunk = it * 256 + t;
      int r = chunk >> 4, cc = ((chunk & 15) ^ (r & 7)) * 8;
      gl2lds16(Kb + (size_t)(kv * 64 + r) * KVD + g * HDIM + cc,
               (char*)&Ks[buf][0] + it * 4096 + wave * 1024);
    }
  };
  auto stage_v = [&](int kv) {
#pragma unroll
    for (int it = 0; it < 4; ++it) {
      int chunk = it * 256 + t;
      int d = chunk >> 3, cc = ((chunk & 7) ^ (d & 7)) * 8;
      gl2lds16(Vtg + (size_t)(g * HDIM + d) * SEQ + kv * 64 + cc,
               (char*)Vs + it * 4096 + wave * 1024);
    }
  };

  auto soft_pv = [&](f4v (&s)[4], int qt, int kv, f4v (&acc_o)[9], float& mrun) {
    __hip_bfloat16* P = &Ps[wave][0];
    const bool diag = (kv == qt);
    const int qi = qt * 64 + wave * 16 + lrow;
    const int swz = (lrow & 7) << 3;
    float pv[4][4];
    float mx = -1e30f;
#pragma unroll
    for (int n = 0; n < 4; ++n)
#pragma unroll
      for (int j = 0; j < 4; ++j) {
        float v = s[n][j];
        if (diag) {
          int ki = kv * 64 + n * 16 + kq * 4 + j;
          if (ki > qi) v = -1e30f;
        }
        pv[n][j] = v;
        mx = fmaxf(mx, v);
      }
    mx = fmaxf(mx, __shfl_xor(mx, 16, 64));
    mx = fmaxf(mx, __shfl_xor(mx, 32, 64));
    if (!__all(mx <= mrun)) {
      float mnew = fmaxf(mrun, mx);
      float fsc = __expf(mrun - mnew);
      mrun = mnew;
      float fj[4];
#pragma unroll
      for (int j = 0; j < 4; ++j) fj[j] = __shfl(fsc, kq * 4 + j, 64);
#pragma unroll
      for (int n = 0; n < 9; ++n) {
        acc_o[n][0] *= fj[0]; acc_o[n][1] *= fj[1];
        acc_o[n][2] *= fj[2]; acc_o[n][3] *= fj[3];
      }
    }
    asm volatile("" ::: "memory");
#pragma unroll
    for (int n = 0; n < 4; ++n) {
      union { __hip_bfloat16 b[4]; s4v v; } u;
#pragma unroll
      for (int j = 0; j < 4; ++j) u.b[j] = __float2bfloat16(__expf(pv[n][j] - mrun));
      *(s4v*)&P[lrow * 64 + ((n * 16 + kq * 4) ^ swz)] = u.v;
    }
    asm volatile("" ::: "memory");
#pragma unroll
    for (int tt = 0; tt < 2; ++tt) {
      s8v pa = *(const s8v*)&P[lrow * 64 + ((tt * 32 + kq * 8) ^ swz)];
#pragma unroll
      for (int n = 0; n < 9; ++n) {          // n==8: ones rows -> l accumulation
        int d = n * 16 + lrow;
        s8v vf = *(const s8v*)&Vs[d * 64 + ((tt * 32 + kq * 8) ^ ((d & 7) << 3))];
        MFMA16(acc_o[n], pa, vf);
      }
    }
  };

  stage_k(0, 0);
  int cur = 0;
  for (int kv = 0; kv <= qtB; ++kv) {
    const bool actA = (kv <= qtA);
    __syncthreads();
    if (kv < qtB) stage_k(cur ^ 1, kv + 1);
    stage_v(kv);

    f4v sB[4] = {}, sA[4] = {};
    if (actA) {
#pragma unroll
      for (int tt = 0; tt < 4; ++tt)
#pragma unroll
        for (int n = 0; n < 4; ++n) {
          int row = n * 16 + lrow;
          s8v kf = *(const s8v*)&Ks[cur][row * 128 + ((tt * 32 + kq * 8) ^ ((row & 7) << 3))];
          MFMA16(sB[n], kf, qfB[tt]);
          MFMA16(sA[n], kf, qfA[tt]);
        }
    } else {
#pragma unroll
      for (int tt = 0; tt < 4; ++tt)
#pragma unroll
        for (int n = 0; n < 4; ++n) {
          int row = n * 16 + lrow;
          s8v kf = *(const s8v*)&Ks[cur][row * 128 + ((tt * 32 + kq * 8) ^ ((row & 7) << 3))];
          MFMA16(sB[n], kf, qfB[tt]);
        }
    }
    __syncthreads();

    soft_pv(sB, qtB, kv, oB, mB);
    if (actA) soft_pv(sA, qtA, kv, oA, mA);
    cur ^= 1;
  }

#pragma unroll
  for (int n = 0; n < 8; ++n)
#pragma unroll
    for (int j = 0; j < 4; ++j) {
      int d = n * 16 + lrow;
      int qiB = qtB * 64 + wave * 16 + kq * 4 + j;
      O[(size_t)qiB * QD + h * HDIM + d] = __float2bfloat16(oB[n][j] / oB[8][j]);
      int qiA = qtA * 64 + wave * 16 + kq * 4 + j;
      O[(size_t)qiA * QD + h * HDIM + d] = __float2bfloat16(oA[n][j] / oA[8][j]);
    }
}

// ---------------- launch ----------------
extern "C" void kernel_launch(void* const* d_in, const int* in_sizes, int n_in,
                              void* d_out, int out_size, void* d_ws, size_t ws_size,
                              hipStream_t stream) {
  const float* x  = (const float*)d_in[0];
  const float* fc = (const float*)d_in[1];
  const float* fs = (const float*)d_in[2];
  const float* wq = (const float*)d_in[3];
  const float* wk = (const float*)d_in[4];
  const float* wv = (const float*)d_in[5];
  const float* wo = (const float*)d_in[6];
  float* out = (float*)d_out;

  char* ws = (char*)d_ws;
  auto alloc = [&](size_t bytes) {
    char* p = ws;
    ws += (bytes + 255) & ~(size_t)255;
    return p;
  };
  __hip_bfloat16* xb  = (__hip_bfloat16*)alloc((size_t)SEQ * DMODEL * 2);
  __hip_bfloat16* wf  = (__hip_bfloat16*)alloc((size_t)QKVN * DMODEL * 2);
  __hip_bfloat16* wob = (__hip_bfloat16*)alloc((size_t)DMODEL * QD * 2);
  __hip_bfloat16* Qb  = (__hip_bfloat16*)alloc((size_t)SEQ * QD * 2);
  __hip_bfloat16* Kc  = (__hip_bfloat16*)alloc((size_t)SEQ * KVD * 2);
  __hip_bfloat16* Vtg = (__hip_bfloat16*)alloc((size_t)KVD * SEQ * 2);
  __hip_bfloat16* Ob  = (__hip_bfloat16*)alloc((size_t)SEQ * QD * 2);
  float2*         fp  = (float2*)alloc((size_t)SEQ * 64 * 8);

  // 6291456 cvt units + 16384 pack units = 6307840 -> 24640 blocks
  k_cvt5<<<dim3(24640), dim3(256), 0, stream>>>(x, wq, wk, wv, wo, fc, fs, xb, wf, wob, fp);

  k_qkv<<<dim3(256), dim3(512), 0, stream>>>(xb, wf, fp, Qb, Kc, Vtg);

  k_flash<<<dim3(16, NH), 256, 0, stream>>>(Qb, Kc, Vtg, Ob);

  k_oproj<<<dim3(DMODEL / 256, SEQ / 128), dim3(512), 0, stream>>>(Ob, wob, out);
}